// Round 7
// baseline (2109.077 us; speedup 1.0000x reference)
//
#include <hip/hip_runtime.h>
#include <hip/hip_bf16.h>
#include <math.h>

#define HWsz 4096
#define Csz  256
#define BZsz 4
#define Msz  1024
#define Ksz  3072

// ---------------------------------------------------------------------------
// K0: transpose input [b][c][p] -> inpT [b][p][c]
// ---------------------------------------------------------------------------
__global__ void transpose_kernel(const float* __restrict__ in, float* __restrict__ outT) {
    __shared__ float tile[32][33];
    int b  = blockIdx.z;
    int p0 = blockIdx.x * 32;
    int c0 = blockIdx.y * 32;
    int tx = threadIdx.x;  // 32
    int ty = threadIdx.y;  // 8
#pragma unroll
    for (int i = 0; i < 4; i++) {
        int c = c0 + ty + i * 8;
        tile[ty + i * 8][tx] = in[((size_t)b * Csz + c) * HWsz + p0 + tx];
    }
    __syncthreads();
#pragma unroll
    for (int i = 0; i < 4; i++) {
        int p = p0 + ty + i * 8;
        outT[((size_t)b * HWsz + p) * Csz + c0 + tx] = tile[tx][ty + i * 8];
    }
}

// ---------------------------------------------------------------------------
// K1: np.linalg.norm(x, axis=0) replica: f32 square (rounded mult), STRICTLY
// SEQUENTIAL f32 sum over c ascending (numpy axis-0 reduce: outer loop over
// rows, vectorized over columns -> per column a sequential f32 add chain),
// IEEE f32 sqrt, + 1e-8f (weak scalar).
// ---------------------------------------------------------------------------
__global__ void colnorm_kernel(const float* __restrict__ inp, float* __restrict__ dnorm) {
#pragma clang fp contract(off)
    int p = blockIdx.x * 256 + threadIdx.x;   // 0..HW-1
    int b = blockIdx.y;
    const float* col = inp + (size_t)b * Csz * HWsz + p;
    float acc = 0.f;
    for (int c = 0; c < Csz; c++) {
        float x  = col[(size_t)c * HWsz];
        float sq = x * x;          // rounded f32 multiply (np: x.conj()*x)
        acc = acc + sq;            // sequential f32 add (contract off)
    }
    dnorm[b * HWsz + p] = sqrtf(acc) + 1e-8f;
}

// ---------------------------------------------------------------------------
// K2: sim replica of np.einsum('ck,cp->pk') with optimize=False:
// inner loop = AXPY over k (contig), accumulation over c SEQUENTIAL ascending,
// single f32 accumulator per (p,k), SEPARATE f32 mul + f32 add (baseline-SIMD
// numpy wheel: npyv_muladd = mul+add, NO FMA). kn = known/dn IEEE f32 div.
// First-max argmax over ascending k. block: 256 thr, 64-pixel tile.
// ---------------------------------------------------------------------------
__launch_bounds__(256, 1)
__global__ void sim_argmax_kernel(const float* __restrict__ inp,
                                  const float* __restrict__ refm,
                                  const int*   __restrict__ kidx,
                                  const float* __restrict__ dnorm,
                                  float* __restrict__ vmax, int* __restrict__ ind) {
#pragma clang fp contract(off)
    __shared__ float rf[Csz * 64];
    __shared__ float kn[Csz * 64];
    __shared__ float s_vals[64 * 16];
    __shared__ int   s_idxs[64 * 16];

    int b   = blockIdx.x;
    int p0  = blockIdx.y * 64;
    int tid = threadIdx.x;
    int pp  = tid & 63;
    int cq  = tid >> 6;  // 0..3

    // stage ref tile: rf[c][pp]
    for (int i = 0; i < 64; i++) {
        int c = cq + i * 4;
        rf[c * 64 + pp] = refm[((size_t)b * Csz + c) * HWsz + p0 + pp];
    }

    int tr = tid >> 4;   // 0..15 : p group
    int tc = tid & 15;   // 0..15 : k group
    float best[4];
    int   bidx[4];
#pragma unroll
    for (int i = 0; i < 4; i++) { best[i] = -INFINITY; bidx[i] = 0x7fffffff; }

    for (int kb = 0; kb < Ksz; kb += 64) {
        __syncthreads();
        // stage normalized known chunk: kn[c][pp] = raw / dn (IEEE f32 div)
        int kid = kidx[kb + pp];
        float dn = dnorm[b * HWsz + kid];
        const float* src = inp + (size_t)b * Csz * HWsz + kid;
        for (int i = 0; i < 64; i++) {
            int c = cq + i * 4;
            kn[c * 64 + pp] = src[(size_t)c * HWsz] / dn;
        }
        __syncthreads();

        float acc[4][4];
#pragma unroll
        for (int i = 0; i < 4; i++)
#pragma unroll
            for (int j = 0; j < 4; j++) acc[i][j] = 0.f;

#pragma unroll 2
        for (int c = 0; c < Csz; c++) {
            float4 a  = *(const float4*)&rf[c * 64 + tr * 4];
            float4 bb = *(const float4*)&kn[c * 64 + tc * 4];
            float av[4] = {a.x, a.y, a.z, a.w};
            float bv[4] = {bb.x, bb.y, bb.z, bb.w};
#pragma unroll
            for (int i = 0; i < 4; i++)
#pragma unroll
                for (int j = 0; j < 4; j++) {
                    float pr = av[i] * bv[j];          // f32 mul (rounded)
                    acc[i][j] = acc[i][j] + pr;        // f32 add (no fma!)
                }
        }
#pragma unroll
        for (int j = 0; j < 4; j++) {
            int k = kb + tc * 4 + j;
#pragma unroll
            for (int i = 0; i < 4; i++) {
                float v = acc[i][j];
                if (v > best[i] || (v == best[i] && k < bidx[i])) { best[i] = v; bidx[i] = k; }
            }
        }
    }

    __syncthreads();
#pragma unroll
    for (int i = 0; i < 4; i++) {
        int p = tr * 4 + i;
        s_vals[p * 16 + tc] = best[i];
        s_idxs[p * 16 + tc] = bidx[i];
    }
    __syncthreads();
    if (tid < 64) {
        float bv = -INFINITY; int bi = 0x7fffffff;
        for (int t = 0; t < 16; t++) {
            float v = s_vals[tid * 16 + t];
            int   k = s_idxs[tid * 16 + t];
            if (v > bv || (v == bv && k < bi)) { bv = v; bi = k; }
        }
        vmax[b * HWsz + p0 + tid] = bv;
        ind [b * HWsz + p0 + tid] = bi;
    }
}

// ---------------------------------------------------------------------------
// K3: serial scan, one wave per image. `at` replicates OpenBLAS x86_64 sdot
// STRIDED branch (u_t = un.T[t] has inc=1024, bypasses the microkernel):
//   2-way unrolled pair loop, F32 accumulator, gcc -ffp-contract=fast:
//     r_q = fmaf(y[2q], x[2q], fl32(y[2q+1]*x[2q+1]));  dot = fl32(dot + r_q)
//   pairs q ascending (c = 2q, 2q+1), n=256 -> no scalar tail.
// Pair terms computed in parallel (2/lane), serial 128-add chain run
// redundantly by all lanes from LDS (bit-exact, adds not reassociable).
// All scalar ops f32 in reference order (contract off): u = raw/dn,
// denom = at+vm, a_new = at/denom, a_ori = vm/denom, out = mul, mul, add.
// Output for masked pixel t == the f32 carry after step t.
// ---------------------------------------------------------------------------
__launch_bounds__(64)
__global__ void scan_kernel(const float* __restrict__ inpT, const float* __restrict__ dnorm,
                            const float* __restrict__ vmax, const int* __restrict__ ind,
                            const int* __restrict__ midx, const int* __restrict__ kidx,
                            float* __restrict__ outT) {
#pragma clang fp contract(off)
    __shared__ float L_vm[Msz];
    __shared__ float L_dn[Msz];
    __shared__ int   L_ur[Msz];
    __shared__ int   L_bk[Msz];
    __shared__ float rbuf[128];
    int b    = blockIdx.x;
    int lane = threadIdx.x;

    for (int t0 = 0; t0 < Msz; t0 += 64) {
        int t  = t0 + lane;
        int pp = midx[t];
        L_ur[t] = pp;
        L_dn[t] = dnorm[b * HWsz + pp];
        L_vm[t] = vmax[b * HWsz + pp];
        L_bk[t] = kidx[ind[b * HWsz + pp]];
    }
    __syncthreads();

    const float* base = inpT + (size_t)b * HWsz * Csz + lane * 4;
    float o0 = 0.f, o1 = 0.f, o2 = 0.f, o3 = 0.f;
    float4 U[4], Bk[4];
#pragma unroll
    for (int s = 0; s < 4; s++) {
        U[s]  = *(const float4*)(base + (size_t)L_ur[s] * Csz);
        Bk[s] = *(const float4*)(base + (size_t)L_bk[s] * Csz);
    }

    for (int t = 0; t < Msz; t += 4) {
#pragma unroll
        for (int s = 0; s < 4; s++) {
            int tt = t + s;
            float dn = L_dn[tt];
            // u = raw / dn, IEEE f32 division (un matrix elementwise divide)
            float u0 = U[s].x / dn, u1 = U[s].y / dn, u2 = U[s].z / dn, u3 = U[s].w / dn;
            // sdot strided pair terms: r = fmaf(y0,x0, fl(y1*x1)); 2 pairs/lane
            float pA = u1 * o1;                           // f32 mul
            float rA = __builtin_fmaf(u0, o0, pA);        // fused
            float pB = u3 * o3;
            float rB = __builtin_fmaf(u2, o2, pB);
            rbuf[2 * lane]     = rA;
            rbuf[2 * lane + 1] = rB;
            __syncthreads();
            // sequential f32 accumulator, pairs ascending (all lanes redundant)
            float dot = 0.f;
#pragma unroll
            for (int q = 0; q < 128; q++) dot = dot + rbuf[q];
            __syncthreads();
            float at    = dot;
            float vm    = L_vm[tt];
            float denom = at + vm;      // f32 add
            float anew  = at / denom;   // IEEE f32 div
            float aori  = vm / denom;   // IEEE f32 div
            // out = a_new*prev_out + a_ori*bk : mul, mul, add (contract off)
            float m0 = anew * o0, n0 = aori * Bk[s].x;
            float m1 = anew * o1, n1 = aori * Bk[s].y;
            float m2 = anew * o2, n2 = aori * Bk[s].z;
            float m3 = anew * o3, n3 = aori * Bk[s].w;
            o0 = m0 + n0; o1 = m1 + n1; o2 = m2 + n2; o3 = m3 + n3;
            float4 w = {o0, o1, o2, o3};
            *(float4*)&outT[((size_t)b * Msz + tt) * Csz + lane * 4] = w;
            if (tt + 4 < Msz) {   // software-pipelined prefetch, distance 4
                U[s]  = *(const float4*)(base + (size_t)L_ur[tt + 4] * Csz);
                Bk[s] = *(const float4*)(base + (size_t)L_bk[tt + 4] * Csz);
            }
        }
    }
}

// ---------------------------------------------------------------------------
// K4: mask position map
// ---------------------------------------------------------------------------
__global__ void maskpos_init(int* mp) { mp[blockIdx.x * 256 + threadIdx.x] = -1; }
__global__ void maskpos_set(const int* __restrict__ midx, int* mp) {
    int t = blockIdx.x * 256 + threadIdx.x;
    if (t < Msz) mp[midx[t]] = t;
}

// ---------------------------------------------------------------------------
// K5: assemble output [b][c][p]: masked -> scan carry row, known -> gathered col
// ---------------------------------------------------------------------------
#define FSTR 261
__launch_bounds__(256)
__global__ void finalize_kernel(const float* __restrict__ inpT, const float* __restrict__ outT,
                                const int* __restrict__ ind, const int* __restrict__ kidx,
                                const int* __restrict__ mp, float* __restrict__ out) {
    __shared__ float tile[64 * FSTR];
    int b   = blockIdx.x;
    int p0  = blockIdx.y * 64;
    int tid = threadIdx.x;
    int rl  = tid >> 6;          // 0..3
    int cc  = (tid & 63) * 4;    // float4 col offset
    for (int i = 0; i < 16; i++) {
        int r = rl + i * 4;
        int p = p0 + r;
        int m = mp[p];
        const float* src = (m >= 0) ? (outT + ((size_t)b * Msz + m) * Csz)
                                    : (inpT + ((size_t)b * HWsz + kidx[ind[b * HWsz + p]]) * Csz);
        float4 v = *(const float4*)(src + cc);
        tile[r * FSTR + cc + 0] = v.x;
        tile[r * FSTR + cc + 1] = v.y;
        tile[r * FSTR + cc + 2] = v.z;
        tile[r * FSTR + cc + 3] = v.w;
    }
    __syncthreads();
    int pp = tid & 63;
    int c0 = tid >> 6;
    for (int i = 0; i < 64; i++) {
        int c = c0 + i * 4;
        out[((size_t)b * Csz + c) * HWsz + p0 + pp] = tile[pp * FSTR + c];
    }
}

// ---------------------------------------------------------------------------
extern "C" void kernel_launch(void* const* d_in, const int* in_sizes, int n_in,
                              void* d_out, int out_size, void* d_ws, size_t ws_size,
                              hipStream_t stream) {
    const float* inp  = (const float*)d_in[0];
    const float* refm = (const float*)d_in[1];
    const int*   midx = (const int*)d_in[2];
    const int*   kidx = (const int*)d_in[3];
    float* out = (float*)d_out;

    char* ws = (char*)d_ws;
    float* inpT  = (float*)(ws);                  // BZ*HW*C f32 = 16 MB   (ends 16777216)
    float* outT  = (float*)(ws + 16777216);       // BZ*M*C  f32 =  4 MB   (ends 20971520)
    float* dnorm = (float*)(ws + 20971520);       // BZ*HW f32 = 64 KB     (ends 21037056)
    float* vmax  = (float*)(ws + 21037056);       // BZ*HW f32 = 64 KB     (ends 21102592)
    int*   ind   = (int*)  (ws + 21102592);       // BZ*HW i32 = 64 KB     (ends 21168128)
    int*   mp    = (int*)  (ws + 21168128);       // HW i32 = 16 KB        (ends 21184512)

    hipLaunchKernelGGL(transpose_kernel, dim3(HWsz / 32, Csz / 32, BZsz), dim3(32, 8), 0, stream,
                       inp, inpT);
    hipLaunchKernelGGL(maskpos_init, dim3(HWsz / 256), dim3(256), 0, stream, mp);
    hipLaunchKernelGGL(maskpos_set, dim3((Msz + 255) / 256), dim3(256), 0, stream, midx, mp);
    hipLaunchKernelGGL(colnorm_kernel, dim3(HWsz / 256, BZsz), dim3(256), 0, stream, inp, dnorm);
    hipLaunchKernelGGL(sim_argmax_kernel, dim3(BZsz, HWsz / 64), dim3(256), 0, stream,
                       inp, refm, kidx, dnorm, vmax, ind);
    hipLaunchKernelGGL(scan_kernel, dim3(BZsz), dim3(64), 0, stream,
                       inpT, dnorm, vmax, ind, midx, kidx, outT);
    hipLaunchKernelGGL(finalize_kernel, dim3(BZsz, HWsz / 64), dim3(256), 0, stream,
                       inpT, outT, ind, kidx, mp, out);
}

// Round 8
// 1554.606 us; speedup vs baseline: 1.3567x; 1.3567x over previous
//
#include <hip/hip_runtime.h>
#include <hip/hip_bf16.h>
#include <math.h>

#define HWsz 4096
#define Csz  256
#define BZsz 4
#define Msz  1024
#define Ksz  3072
#define KSPL 4
#define KPER 768      // Ksz / KSPL
#define NKT  6        // KPER / 128
#define LDP  132      // padded LDS row (floats)

// ---------------------------------------------------------------------------
// K0: transpose input [b][c][p] -> inpT [b][p][c]
// ---------------------------------------------------------------------------
__global__ void transpose_kernel(const float* __restrict__ in, float* __restrict__ outT) {
    __shared__ float tile[32][33];
    int b  = blockIdx.z;
    int p0 = blockIdx.x * 32;
    int c0 = blockIdx.y * 32;
    int tx = threadIdx.x;  // 32
    int ty = threadIdx.y;  // 8
#pragma unroll
    for (int i = 0; i < 4; i++) {
        int c = c0 + ty + i * 8;
        tile[ty + i * 8][tx] = in[((size_t)b * Csz + c) * HWsz + p0 + tx];
    }
    __syncthreads();
#pragma unroll
    for (int i = 0; i < 4; i++) {
        int p = p0 + ty + i * 8;
        outT[((size_t)b * HWsz + p) * Csz + c0 + tx] = tile[tx][ty + i * 8];
    }
}

// ---------------------------------------------------------------------------
// K1: norm replica: f32 square (rounded mult), STRICTLY SEQUENTIAL f32 sum
// over c ascending, IEEE f32 sqrt, + 1e-8f.  (unchanged numerics)
// ---------------------------------------------------------------------------
__global__ void colnorm_kernel(const float* __restrict__ inp, float* __restrict__ dnorm) {
#pragma clang fp contract(off)
    int p = blockIdx.x * 256 + threadIdx.x;   // 0..HW-1
    int b = blockIdx.y;
    const float* col = inp + (size_t)b * Csz * HWsz + p;
    float acc = 0.f;
    for (int c = 0; c < Csz; c++) {
        float x  = col[(size_t)c * HWsz];
        float sq = x * x;
        acc = acc + sq;
    }
    dnorm[b * HWsz + p] = sqrtf(acc) + 1e-8f;
}

// ---------------------------------------------------------------------------
// K2 v2: sim einsum replica, K-split for occupancy.
// grid (BZ, HW/128, KSPL), 256 thr, 2 blocks/CU (66KB LDS).
// Per (p,k): single f32 accumulator, mul+add (NO fma), c ascending (4 chunks
// of 64, ascending). Per-thread 8p x 8k micro-tile. Partial first-max argmax
// per split (k ascending within split), combined later ascending splits.
// ---------------------------------------------------------------------------
__launch_bounds__(256, 2)
__global__ void sim_argmax_kernel(const float* __restrict__ inpT,
                                  const float* __restrict__ refm,
                                  const int*   __restrict__ kidx,
                                  const float* __restrict__ dnorm,
                                  float* __restrict__ pvmax, int* __restrict__ pind) {
#pragma clang fp contract(off)
    __shared__ float rf[64][LDP];   // [c][p]
    __shared__ float kn[64][LDP];   // [c][k]

    int b   = blockIdx.x;
    int p0  = blockIdx.y * 128;
    int ks  = blockIdx.z;
    int k0  = ks * KPER;
    int tid = threadIdx.x;

    int tr = tid >> 4;          // 0..15 -> p = p0 + tr*8 + i
    int tc = tid & 15;          // 0..15 -> k = tile_k0 + tc*8 + j

    // staging roles
    int spp = tid & 127;        // rf: pixel col
    int sch = tid >> 7;         // rf: row parity
    int skk = tid >> 1;         // kn: k row (0..127)
    int sc4 = (tid & 1) * 32;   // kn: c offset (0 or 32)

    float best[8];
    int   bidx[8];
#pragma unroll
    for (int i = 0; i < 8; i++) { best[i] = -INFINITY; bidx[i] = 0x7fffffff; }

    for (int kt = 0; kt < NKT; kt++) {
        int ktbase = k0 + kt * 128;
        int kid = kidx[ktbase + skk];
        float dn = dnorm[b * HWsz + kid];
        const float* nrow = inpT + ((size_t)b * HWsz + kid) * Csz;

        float acc[8][8];
#pragma unroll
        for (int i = 0; i < 8; i++)
#pragma unroll
            for (int j = 0; j < 8; j++) acc[i][j] = 0.f;

        for (int cc = 0; cc < 4; cc++) {
            __syncthreads();
            // stage rf[c][pp] from refm (coalesced)
#pragma unroll 8
            for (int i = 0; i < 32; i++) {
                int c = i * 2 + sch;
                rf[c][spp] = refm[((size_t)b * Csz + cc * 64 + c) * HWsz + p0 + spp];
            }
            // stage kn[c][kk] = inpT[kid][c] / dn  (IEEE f32 div, same bits as ref)
            const float* src = nrow + cc * 64 + sc4;
#pragma unroll
            for (int i = 0; i < 8; i++) {
                float4 v = *(const float4*)(src + i * 4);
                int c = sc4 + i * 4;
                kn[c + 0][skk] = v.x / dn;
                kn[c + 1][skk] = v.y / dn;
                kn[c + 2][skk] = v.z / dn;
                kn[c + 3][skk] = v.w / dn;
            }
            __syncthreads();

#pragma unroll 2
            for (int c = 0; c < 64; c++) {
                float4 a0 = *(const float4*)&rf[c][tr * 8];
                float4 a1 = *(const float4*)&rf[c][tr * 8 + 4];
                float4 b0 = *(const float4*)&kn[c][tc * 8];
                float4 b1 = *(const float4*)&kn[c][tc * 8 + 4];
                float av[8] = {a0.x, a0.y, a0.z, a0.w, a1.x, a1.y, a1.z, a1.w};
                float bv[8] = {b0.x, b0.y, b0.z, b0.w, b1.x, b1.y, b1.z, b1.w};
#pragma unroll
                for (int i = 0; i < 8; i++)
#pragma unroll
                    for (int j = 0; j < 8; j++) {
                        float pr = av[i] * bv[j];     // f32 mul (rounded)
                        acc[i][j] = acc[i][j] + pr;   // f32 add (no fma)
                    }
            }
        }
        // argmax update, k ascending (kt asc, j asc)
#pragma unroll
        for (int j = 0; j < 8; j++) {
            int k = ktbase + tc * 8 + j;
#pragma unroll
            for (int i = 0; i < 8; i++) {
                float v = acc[i][j];
                if (v > best[i] || (v == best[i] && k < bidx[i])) { best[i] = v; bidx[i] = k; }
            }
        }
    }

    // reduce across tc groups (reuse LDS)
    __syncthreads();
    float* sv = &rf[0][0];          // 128p x 16tc
    int*   si = (int*)&kn[0][0];
#pragma unroll
    for (int i = 0; i < 8; i++) {
        int p = tr * 8 + i;
        sv[p * 16 + tc] = best[i];
        si[p * 16 + tc] = bidx[i];
    }
    __syncthreads();
    if (tid < 128) {
        float bv = -INFINITY; int bi = 0x7fffffff;
        for (int t = 0; t < 16; t++) {
            float v = sv[tid * 16 + t];
            int   k = si[tid * 16 + t];
            if (v > bv || (v == bv && k < bi)) { bv = v; bi = k; }
        }
        pvmax[((size_t)ks * BZsz + b) * HWsz + p0 + tid] = bv;
        pind [((size_t)ks * BZsz + b) * HWsz + p0 + tid] = bi;
    }
}

// ---------------------------------------------------------------------------
// K2b: combine K-splits (ascending ks => global first-max)
// ---------------------------------------------------------------------------
__global__ void combine_kernel(const float* __restrict__ pvmax, const int* __restrict__ pind,
                               float* __restrict__ vmax, int* __restrict__ ind) {
    int p = blockIdx.x * 256 + threadIdx.x;
    int b = blockIdx.y;
    float bv = -INFINITY; int bi = 0x7fffffff;
    for (int ks = 0; ks < KSPL; ks++) {
        float v = pvmax[((size_t)ks * BZsz + b) * HWsz + p];
        int   k = pind [((size_t)ks * BZsz + b) * HWsz + p];
        if (v > bv || (v == bv && k < bi)) { bv = v; bi = k; }
    }
    vmax[b * HWsz + p] = bv;
    ind [b * HWsz + p] = bi;
}

// ---------------------------------------------------------------------------
// K3 v2: serial scan, one wave per image. Identical numerics to R7:
//   u = U/dn (IEEE f32 div); pair terms r = fmaf(u_even, o_even, f32(u_odd*o_odd));
//   dot = strictly sequential f32 adds over 128 pair terms ascending;
//   denom = at+vm; IEEE f32 divs; update mul,mul,add (contract off).
// Chain now reads rbuf via 32 x b128 (batched, values identical).
// ---------------------------------------------------------------------------
__launch_bounds__(64)
__global__ void scan_kernel(const float* __restrict__ inpT, const float* __restrict__ dnorm,
                            const float* __restrict__ vmax, const int* __restrict__ ind,
                            const int* __restrict__ midx, const int* __restrict__ kidx,
                            float* __restrict__ outT) {
#pragma clang fp contract(off)
    __shared__ float L_vm[Msz];
    __shared__ float L_dn[Msz];
    __shared__ int   L_ur[Msz];
    __shared__ int   L_bk[Msz];
    __shared__ float4 rbuf4[32];
    float* rbuf = (float*)rbuf4;
    int b    = blockIdx.x;
    int lane = threadIdx.x;

    for (int t0 = 0; t0 < Msz; t0 += 64) {
        int t  = t0 + lane;
        int pp = midx[t];
        L_ur[t] = pp;
        L_dn[t] = dnorm[b * HWsz + pp];
        L_vm[t] = vmax[b * HWsz + pp];
        L_bk[t] = kidx[ind[b * HWsz + pp]];
    }
    __syncthreads();

    const float* base = inpT + (size_t)b * HWsz * Csz + lane * 4;
    float o0 = 0.f, o1 = 0.f, o2 = 0.f, o3 = 0.f;
    float4 U[4], Bk[4];
#pragma unroll
    for (int s = 0; s < 4; s++) {
        U[s]  = *(const float4*)(base + (size_t)L_ur[s] * Csz);
        Bk[s] = *(const float4*)(base + (size_t)L_bk[s] * Csz);
    }

    for (int t = 0; t < Msz; t += 4) {
#pragma unroll
        for (int s = 0; s < 4; s++) {
            int tt = t + s;
            float dn = L_dn[tt];
            float u0 = U[s].x / dn, u1 = U[s].y / dn, u2 = U[s].z / dn, u3 = U[s].w / dn;
            float pA = u1 * o1;
            float rA = __builtin_fmaf(u0, o0, pA);
            float pB = u3 * o3;
            float rB = __builtin_fmaf(u2, o2, pB);
            rbuf[2 * lane]     = rA;
            rbuf[2 * lane + 1] = rB;
            __syncthreads();
            // strictly sequential 128-add chain, batched b128 reads
            float dot = 0.f;
#pragma unroll
            for (int q4 = 0; q4 < 32; q4++) {
                float4 r = rbuf4[q4];
                dot = dot + r.x;
                dot = dot + r.y;
                dot = dot + r.z;
                dot = dot + r.w;
            }
            __syncthreads();
            float at    = dot;
            float vm    = L_vm[tt];
            float denom = at + vm;
            float anew  = at / denom;
            float aori  = vm / denom;
            float m0 = anew * o0, n0 = aori * Bk[s].x;
            float m1 = anew * o1, n1 = aori * Bk[s].y;
            float m2 = anew * o2, n2 = aori * Bk[s].z;
            float m3 = anew * o3, n3 = aori * Bk[s].w;
            o0 = m0 + n0; o1 = m1 + n1; o2 = m2 + n2; o3 = m3 + n3;
            float4 w = {o0, o1, o2, o3};
            *(float4*)&outT[((size_t)b * Msz + tt) * Csz + lane * 4] = w;
            if (tt + 4 < Msz) {
                U[s]  = *(const float4*)(base + (size_t)L_ur[tt + 4] * Csz);
                Bk[s] = *(const float4*)(base + (size_t)L_bk[tt + 4] * Csz);
            }
        }
    }
}

// ---------------------------------------------------------------------------
// K4: mask position map
// ---------------------------------------------------------------------------
__global__ void maskpos_init(int* mp) { mp[blockIdx.x * 256 + threadIdx.x] = -1; }
__global__ void maskpos_set(const int* __restrict__ midx, int* mp) {
    int t = blockIdx.x * 256 + threadIdx.x;
    if (t < Msz) mp[midx[t]] = t;
}

// ---------------------------------------------------------------------------
// K5: assemble output [b][c][p]: masked -> scan carry row, known -> gathered col
// ---------------------------------------------------------------------------
#define FSTR 261
__launch_bounds__(256)
__global__ void finalize_kernel(const float* __restrict__ inpT, const float* __restrict__ outT,
                                const int* __restrict__ ind, const int* __restrict__ kidx,
                                const int* __restrict__ mp, float* __restrict__ out) {
    __shared__ float tile[64 * FSTR];
    int b   = blockIdx.x;
    int p0  = blockIdx.y * 64;
    int tid = threadIdx.x;
    int rl  = tid >> 6;          // 0..3
    int cc  = (tid & 63) * 4;    // float4 col offset
    for (int i = 0; i < 16; i++) {
        int r = rl + i * 4;
        int p = p0 + r;
        int m = mp[p];
        const float* src = (m >= 0) ? (outT + ((size_t)b * Msz + m) * Csz)
                                    : (inpT + ((size_t)b * HWsz + kidx[ind[b * HWsz + p]]) * Csz);
        float4 v = *(const float4*)(src + cc);
        tile[r * FSTR + cc + 0] = v.x;
        tile[r * FSTR + cc + 1] = v.y;
        tile[r * FSTR + cc + 2] = v.z;
        tile[r * FSTR + cc + 3] = v.w;
    }
    __syncthreads();
    int pp = tid & 63;
    int c0 = tid >> 6;
    for (int i = 0; i < 64; i++) {
        int c = c0 + i * 4;
        out[((size_t)b * Csz + c) * HWsz + p0 + pp] = tile[pp * FSTR + c];
    }
}

// ---------------------------------------------------------------------------
extern "C" void kernel_launch(void* const* d_in, const int* in_sizes, int n_in,
                              void* d_out, int out_size, void* d_ws, size_t ws_size,
                              hipStream_t stream) {
    const float* inp  = (const float*)d_in[0];
    const float* refm = (const float*)d_in[1];
    const int*   midx = (const int*)d_in[2];
    const int*   kidx = (const int*)d_in[3];
    float* out = (float*)d_out;

    char* ws = (char*)d_ws;
    float* inpT  = (float*)(ws);                  // 16 MB              (ends 16777216)
    float* outT  = (float*)(ws + 16777216);       // 4 MB               (ends 20971520)
    float* dnorm = (float*)(ws + 20971520);       // 64 KB              (ends 21037056)
    float* vmax  = (float*)(ws + 21037056);       // 64 KB              (ends 21102592)
    int*   ind   = (int*)  (ws + 21102592);       // 64 KB              (ends 21168128)
    int*   mp    = (int*)  (ws + 21168128);       // 16 KB              (ends 21184512)
    float* pvmax = (float*)(ws + 21184512);       // KSPL*BZ*HW = 256KB (ends 21446656)
    int*   pind  = (int*)  (ws + 21446656);       // 256 KB             (ends 21708800)

    hipLaunchKernelGGL(transpose_kernel, dim3(HWsz / 32, Csz / 32, BZsz), dim3(32, 8), 0, stream,
                       inp, inpT);
    hipLaunchKernelGGL(maskpos_init, dim3(HWsz / 256), dim3(256), 0, stream, mp);
    hipLaunchKernelGGL(maskpos_set, dim3((Msz + 255) / 256), dim3(256), 0, stream, midx, mp);
    hipLaunchKernelGGL(colnorm_kernel, dim3(HWsz / 256, BZsz), dim3(256), 0, stream, inp, dnorm);
    hipLaunchKernelGGL(sim_argmax_kernel, dim3(BZsz, HWsz / 128, KSPL), dim3(256), 0, stream,
                       inpT, refm, kidx, dnorm, pvmax, pind);
    hipLaunchKernelGGL(combine_kernel, dim3(HWsz / 256, BZsz), dim3(256), 0, stream,
                       pvmax, pind, vmax, ind);
    hipLaunchKernelGGL(scan_kernel, dim3(BZsz), dim3(64), 0, stream,
                       inpT, dnorm, vmax, ind, midx, kidx, outT);
    hipLaunchKernelGGL(finalize_kernel, dim3(BZsz, HWsz / 64), dim3(256), 0, stream,
                       inpT, outT, ind, kidx, mp, out);
}

// Round 9
// 1363.996 us; speedup vs baseline: 1.5462x; 1.1397x over previous
//
#include <hip/hip_runtime.h>
#include <hip/hip_bf16.h>
#include <math.h>

#define HWsz 4096
#define Csz  256
#define BZsz 4
#define Msz  1024
#define Ksz  3072
#define KSPL 4
#define KPER 768      // Ksz / KSPL
#define NKT  6        // KPER / 128
#define LDP  132      // padded LDS row (floats)

typedef float f32x2 __attribute__((ext_vector_type(2)));

// ---------------------------------------------------------------------------
// K0: transpose input [b][c][p] -> inpT [b][p][c]
// ---------------------------------------------------------------------------
__global__ void transpose_kernel(const float* __restrict__ in, float* __restrict__ outT) {
    __shared__ float tile[32][33];
    int b  = blockIdx.z;
    int p0 = blockIdx.x * 32;
    int c0 = blockIdx.y * 32;
    int tx = threadIdx.x;  // 32
    int ty = threadIdx.y;  // 8
#pragma unroll
    for (int i = 0; i < 4; i++) {
        int c = c0 + ty + i * 8;
        tile[ty + i * 8][tx] = in[((size_t)b * Csz + c) * HWsz + p0 + tx];
    }
    __syncthreads();
#pragma unroll
    for (int i = 0; i < 4; i++) {
        int p = p0 + ty + i * 8;
        outT[((size_t)b * HWsz + p) * Csz + c0 + tx] = tile[tx][ty + i * 8];
    }
}

// ---------------------------------------------------------------------------
// K1: norm replica: f32 square (rounded mult), STRICTLY SEQUENTIAL f32 sum
// over c ascending, IEEE f32 sqrt, + 1e-8f.  (unchanged numerics)
// ---------------------------------------------------------------------------
__global__ void colnorm_kernel(const float* __restrict__ inp, float* __restrict__ dnorm) {
#pragma clang fp contract(off)
    int p = blockIdx.x * 256 + threadIdx.x;   // 0..HW-1
    int b = blockIdx.y;
    const float* col = inp + (size_t)b * Csz * HWsz + p;
    float acc = 0.f;
    for (int c = 0; c < Csz; c++) {
        float x  = col[(size_t)c * HWsz];
        float sq = x * x;
        acc = acc + sq;
    }
    dnorm[b * HWsz + p] = sqrtf(acc) + 1e-8f;
}

// ---------------------------------------------------------------------------
// K1b: knT[b][kk][c] = inpT[b][kidx[kk]][c] / dn  (IEEE f32 div, once)
// grid (Ksz/4, BZ), 256 thr (4 rows/block)
// ---------------------------------------------------------------------------
__global__ void knprep_kernel(const float* __restrict__ inpT, const float* __restrict__ dnorm,
                              const int* __restrict__ kidx, float* __restrict__ knT) {
    int row  = blockIdx.x * 4 + (threadIdx.x >> 6);
    int lane = threadIdx.x & 63;
    int b    = blockIdx.y;
    int kid  = kidx[row];
    float dn = dnorm[b * HWsz + kid];
    const float* src = inpT + ((size_t)b * HWsz + kid) * Csz + lane * 4;
    float4 v = *(const float4*)src;
    float4 w = {v.x / dn, v.y / dn, v.z / dn, v.w / dn};
    *(float4*)(knT + ((size_t)b * Ksz + row) * Csz + lane * 4) = w;
}

// ---------------------------------------------------------------------------
// K2 v3: sim einsum replica with packed-f32 VALU.
// Per (p,k): single f32 accumulator, mul then add (NO fma), c ascending.
// v_pk_mul_f32 / v_pk_add_f32 do two independent IEEE f32 ops -> bit-exact.
// grid (BZ, HW/128, KSPL), 256 thr, 2 blocks/CU.
// ---------------------------------------------------------------------------
#define PK_MUL(dst, s0, s1) asm("v_pk_mul_f32 %0, %1, %2" : "=v"(dst) : "v"(s0), "v"(s1))
#define PK_ADD(dst, s1)     asm("v_pk_add_f32 %0, %0, %1" : "+v"(dst) : "v"(s1))

__launch_bounds__(256, 2)
__global__ void sim_argmax_kernel(const float* __restrict__ knT,
                                  const float* __restrict__ refm,
                                  float* __restrict__ pvmax, int* __restrict__ pind) {
#pragma clang fp contract(off)
    __shared__ float rf[64][LDP];   // [c][p]
    __shared__ float kn[64][LDP];   // [c][k]

    int b   = blockIdx.x;
    int p0  = blockIdx.y * 128;
    int ks  = blockIdx.z;
    int k0  = ks * KPER;
    int tid = threadIdx.x;

    int tr = tid >> 4;          // 0..15 -> p = p0 + tr*8 + i
    int tc = tid & 15;          // 0..15 -> k = tile_k0 + tc*8 + j

    int spp = tid & 127;        // rf: pixel col
    int sch = tid >> 7;         // rf: row parity
    int skk = tid >> 1;         // kn: k row (0..127)
    int sc4 = (tid & 1) * 32;   // kn: c offset (0 or 32)

    float best[8];
    int   bidx[8];
#pragma unroll
    for (int i = 0; i < 8; i++) { best[i] = -INFINITY; bidx[i] = 0x7fffffff; }

    for (int kt = 0; kt < NKT; kt++) {
        int ktbase = k0 + kt * 128;
        const float* nrow = knT + ((size_t)b * Ksz + ktbase + skk) * Csz;

        f32x2 acc[8][4];   // [i][jj] -> j = 2*jj (lo), 2*jj+1 (hi)
#pragma unroll
        for (int i = 0; i < 8; i++)
#pragma unroll
            for (int jj = 0; jj < 4; jj++) acc[i][jj] = (f32x2){0.f, 0.f};

        for (int cc = 0; cc < 4; cc++) {
            __syncthreads();
#pragma unroll 8
            for (int i = 0; i < 32; i++) {
                int c = i * 2 + sch;
                rf[c][spp] = refm[((size_t)b * Csz + cc * 64 + c) * HWsz + p0 + spp];
            }
            const float* src = nrow + cc * 64 + sc4;
#pragma unroll
            for (int i = 0; i < 8; i++) {
                float4 v = *(const float4*)(src + i * 4);
                int c = sc4 + i * 4;
                kn[c + 0][skk] = v.x;
                kn[c + 1][skk] = v.y;
                kn[c + 2][skk] = v.z;
                kn[c + 3][skk] = v.w;
            }
            __syncthreads();

#pragma unroll 2
            for (int c = 0; c < 64; c++) {
                float4 a0 = *(const float4*)&rf[c][tr * 8];
                float4 a1 = *(const float4*)&rf[c][tr * 8 + 4];
                float4 b0 = *(const float4*)&kn[c][tc * 8];
                float4 b1 = *(const float4*)&kn[c][tc * 8 + 4];
                float av[8] = {a0.x, a0.y, a0.z, a0.w, a1.x, a1.y, a1.z, a1.w};
                f32x2 B[4] = {{b0.x, b0.y}, {b0.z, b0.w}, {b1.x, b1.y}, {b1.z, b1.w}};
#pragma unroll
                for (int i = 0; i < 8; i++) {
                    f32x2 av2 = {av[i], av[i]};
#pragma unroll
                    for (int jj = 0; jj < 4; jj++) {
                        f32x2 pr;
                        PK_MUL(pr, av2, B[jj]);       // two IEEE f32 muls
                        PK_ADD(acc[i][jj], pr);       // two IEEE f32 adds
                    }
                }
            }
        }
        // argmax update, k ascending (kt asc, j asc)
#pragma unroll
        for (int j = 0; j < 8; j++) {
            int k = ktbase + tc * 8 + j;
#pragma unroll
            for (int i = 0; i < 8; i++) {
                float v = (j & 1) ? acc[i][j >> 1].y : acc[i][j >> 1].x;
                if (v > best[i] || (v == best[i] && k < bidx[i])) { best[i] = v; bidx[i] = k; }
            }
        }
    }

    // reduce across tc groups (reuse LDS)
    __syncthreads();
    float* sv = &rf[0][0];          // 128p x 16tc
    int*   si = (int*)&kn[0][0];
#pragma unroll
    for (int i = 0; i < 8; i++) {
        int p = tr * 8 + i;
        sv[p * 16 + tc] = best[i];
        si[p * 16 + tc] = bidx[i];
    }
    __syncthreads();
    if (tid < 128) {
        float bv = -INFINITY; int bi = 0x7fffffff;
        for (int t = 0; t < 16; t++) {
            float v = sv[tid * 16 + t];
            int   k = si[tid * 16 + t];
            if (v > bv || (v == bv && k < bi)) { bv = v; bi = k; }
        }
        pvmax[((size_t)ks * BZsz + b) * HWsz + p0 + tid] = bv;
        pind [((size_t)ks * BZsz + b) * HWsz + p0 + tid] = bi;
    }
}

// ---------------------------------------------------------------------------
// K2b: combine K-splits (ascending ks => global first-max)
// ---------------------------------------------------------------------------
__global__ void combine_kernel(const float* __restrict__ pvmax, const int* __restrict__ pind,
                               float* __restrict__ vmax, int* __restrict__ ind) {
    int p = blockIdx.x * 256 + threadIdx.x;
    int b = blockIdx.y;
    float bv = -INFINITY; int bi = 0x7fffffff;
    for (int ks = 0; ks < KSPL; ks++) {
        float v = pvmax[((size_t)ks * BZsz + b) * HWsz + p];
        int   k = pind [((size_t)ks * BZsz + b) * HWsz + p];
        if (v > bv || (v == bv && k < bi)) { bv = v; bi = k; }
    }
    vmax[b * HWsz + p] = bv;
    ind [b * HWsz + p] = bi;
}

// ---------------------------------------------------------------------------
// K2c: scanprep: uT[b][t][c] = inpT[b][midx[t]][c] / dn (IEEE f32 div, same
// bits as before), bkT[b][t][c] = inpT[b][kidx[ind[..]]][c] (raw copy).
// grid (Msz/4, BZ), 256 thr (4 t rows/block).
// ---------------------------------------------------------------------------
__global__ void scanprep_kernel(const float* __restrict__ inpT, const float* __restrict__ dnorm,
                                const int* __restrict__ ind, const int* __restrict__ midx,
                                const int* __restrict__ kidx,
                                float* __restrict__ uT, float* __restrict__ bkT) {
    int t    = blockIdx.x * 4 + (threadIdx.x >> 6);
    int lane = threadIdx.x & 63;
    int b    = blockIdx.y;
    int pp   = midx[t];
    float dn = dnorm[b * HWsz + pp];
    int bkid = kidx[ind[b * HWsz + pp]];
    const float* us = inpT + ((size_t)b * HWsz + pp) * Csz + lane * 4;
    const float* bs = inpT + ((size_t)b * HWsz + bkid) * Csz + lane * 4;
    float4 v = *(const float4*)us;
    float4 w = {v.x / dn, v.y / dn, v.z / dn, v.w / dn};
    *(float4*)(uT  + ((size_t)b * Msz + t) * Csz + lane * 4) = w;
    *(float4*)(bkT + ((size_t)b * Msz + t) * Csz + lane * 4) = *(const float4*)bs;
}

// ---------------------------------------------------------------------------
// K3 v3: serial scan, one wave per image. Numerics identical to R7/R8:
//   pair terms r = fmaf(u_even, o_even, f32(u_odd*o_odd)); dot = strictly
//   sequential f32 adds over 128 pair terms ascending; denom = at+vm;
//   IEEE f32 divs; update mul,mul,add (contract off).
// Divisions hoisted to scanprep; rbuf double-buffered (1 barrier/step);
// chain reads batched into registers (launch_bounds(64,1) frees VGPRs).
// ---------------------------------------------------------------------------
__launch_bounds__(64, 1)
__global__ void scan_kernel(const float* __restrict__ uT, const float* __restrict__ bkT,
                            const float* __restrict__ vmax, const int* __restrict__ midx,
                            float* __restrict__ outT) {
#pragma clang fp contract(off)
    __shared__ float L_vm[Msz];
    __shared__ float rbuf[2][128];
    int b    = blockIdx.x;
    int lane = threadIdx.x;

    for (int t0 = 0; t0 < Msz; t0 += 64) {
        int t = t0 + lane;
        L_vm[t] = vmax[b * HWsz + midx[t]];
    }
    __syncthreads();

    const float* ub = uT  + (size_t)b * Msz * Csz + lane * 4;
    const float* bb = bkT + (size_t)b * Msz * Csz + lane * 4;
    float o0 = 0.f, o1 = 0.f, o2 = 0.f, o3 = 0.f;
    float4 U[4], Bk[4];
#pragma unroll
    for (int s = 0; s < 4; s++) {
        U[s]  = *(const float4*)(ub + (size_t)s * Csz);
        Bk[s] = *(const float4*)(bb + (size_t)s * Csz);
    }

    for (int t = 0; t < Msz; t += 4) {
#pragma unroll
        for (int s = 0; s < 4; s++) {
            int tt = t + s;
            float4 u = U[s];
            // sdot strided pair terms: r = fmaf(y0,x0, fl(y1*x1)); 2 pairs/lane
            float pA = u.y * o1;
            float rA = __builtin_fmaf(u.x, o0, pA);
            float pB = u.w * o3;
            float rB = __builtin_fmaf(u.z, o2, pB);
            float2 w2; w2.x = rA; w2.y = rB;
            *(float2*)&rbuf[tt & 1][2 * lane] = w2;
            __syncthreads();
            // batched reads, then strictly sequential 128-add chain
            float4 R[32];
#pragma unroll
            for (int q4 = 0; q4 < 32; q4++) R[q4] = ((const float4*)rbuf[tt & 1])[q4];
            float dot = 0.f;
#pragma unroll
            for (int q4 = 0; q4 < 32; q4++) {
                dot = dot + R[q4].x;
                dot = dot + R[q4].y;
                dot = dot + R[q4].z;
                dot = dot + R[q4].w;
            }
            float at    = dot;
            float vm    = L_vm[tt];
            float denom = at + vm;      // f32 add
            float anew  = at / denom;   // IEEE f32 div
            float aori  = vm / denom;   // IEEE f32 div
            float m0 = anew * o0, n0 = aori * Bk[s].x;
            float m1 = anew * o1, n1 = aori * Bk[s].y;
            float m2 = anew * o2, n2 = aori * Bk[s].z;
            float m3 = anew * o3, n3 = aori * Bk[s].w;
            o0 = m0 + n0; o1 = m1 + n1; o2 = m2 + n2; o3 = m3 + n3;
            float4 w = {o0, o1, o2, o3};
            *(float4*)&outT[((size_t)b * Msz + tt) * Csz + lane * 4] = w;
            if (tt + 4 < Msz) {
                U[s]  = *(const float4*)(ub + (size_t)(tt + 4) * Csz);
                Bk[s] = *(const float4*)(bb + (size_t)(tt + 4) * Csz);
            }
        }
    }
}

// ---------------------------------------------------------------------------
// K4: mask position map
// ---------------------------------------------------------------------------
__global__ void maskpos_init(int* mp) { mp[blockIdx.x * 256 + threadIdx.x] = -1; }
__global__ void maskpos_set(const int* __restrict__ midx, int* mp) {
    int t = blockIdx.x * 256 + threadIdx.x;
    if (t < Msz) mp[midx[t]] = t;
}

// ---------------------------------------------------------------------------
// K5: assemble output [b][c][p]: masked -> scan carry row, known -> gathered col
// ---------------------------------------------------------------------------
#define FSTR 261
__launch_bounds__(256)
__global__ void finalize_kernel(const float* __restrict__ inpT, const float* __restrict__ outT,
                                const int* __restrict__ ind, const int* __restrict__ kidx,
                                const int* __restrict__ mp, float* __restrict__ out) {
    __shared__ float tile[64 * FSTR];
    int b   = blockIdx.x;
    int p0  = blockIdx.y * 64;
    int tid = threadIdx.x;
    int rl  = tid >> 6;          // 0..3
    int cc  = (tid & 63) * 4;    // float4 col offset
    for (int i = 0; i < 16; i++) {
        int r = rl + i * 4;
        int p = p0 + r;
        int m = mp[p];
        const float* src = (m >= 0) ? (outT + ((size_t)b * Msz + m) * Csz)
                                    : (inpT + ((size_t)b * HWsz + kidx[ind[b * HWsz + p]]) * Csz);
        float4 v = *(const float4*)(src + cc);
        tile[r * FSTR + cc + 0] = v.x;
        tile[r * FSTR + cc + 1] = v.y;
        tile[r * FSTR + cc + 2] = v.z;
        tile[r * FSTR + cc + 3] = v.w;
    }
    __syncthreads();
    int pp = tid & 63;
    int c0 = tid >> 6;
    for (int i = 0; i < 64; i++) {
        int c = c0 + i * 4;
        out[((size_t)b * Csz + c) * HWsz + p0 + pp] = tile[pp * FSTR + c];
    }
}

// ---------------------------------------------------------------------------
extern "C" void kernel_launch(void* const* d_in, const int* in_sizes, int n_in,
                              void* d_out, int out_size, void* d_ws, size_t ws_size,
                              hipStream_t stream) {
    const float* inp  = (const float*)d_in[0];
    const float* refm = (const float*)d_in[1];
    const int*   midx = (const int*)d_in[2];
    const int*   kidx = (const int*)d_in[3];
    float* out = (float*)d_out;

    char* ws = (char*)d_ws;
    float* inpT  = (float*)(ws);                  // 16 MB   (ends 16777216)
    float* outT  = (float*)(ws + 16777216);       // 4 MB    (ends 20971520)
    float* knT   = (float*)(ws + 20971520);       // 12 MB   (ends 33554432)
    float* uT    = (float*)(ws + 33554432);       // 4 MB    (ends 37748736)
    float* bkT   = (float*)(ws + 37748736);       // 4 MB    (ends 41943040)
    float* dnorm = (float*)(ws + 41943040);       // 64 KB   (ends 42008576)
    float* vmax  = (float*)(ws + 42008576);       // 64 KB   (ends 42074112)
    int*   ind   = (int*)  (ws + 42074112);       // 64 KB   (ends 42139648)
    int*   mp    = (int*)  (ws + 42139648);       // 16 KB   (ends 42156032)
    float* pvmax = (float*)(ws + 42156032);       // 256 KB  (ends 42418176)
    int*   pind  = (int*)  (ws + 42418176);       // 256 KB  (ends 42680320)

    hipLaunchKernelGGL(transpose_kernel, dim3(HWsz / 32, Csz / 32, BZsz), dim3(32, 8), 0, stream,
                       inp, inpT);
    hipLaunchKernelGGL(maskpos_init, dim3(HWsz / 256), dim3(256), 0, stream, mp);
    hipLaunchKernelGGL(maskpos_set, dim3((Msz + 255) / 256), dim3(256), 0, stream, midx, mp);
    hipLaunchKernelGGL(colnorm_kernel, dim3(HWsz / 256, BZsz), dim3(256), 0, stream, inp, dnorm);
    hipLaunchKernelGGL(knprep_kernel, dim3(Ksz / 4, BZsz), dim3(256), 0, stream,
                       inpT, dnorm, kidx, knT);
    hipLaunchKernelGGL(sim_argmax_kernel, dim3(BZsz, HWsz / 128, KSPL), dim3(256), 0, stream,
                       knT, refm, pvmax, pind);
    hipLaunchKernelGGL(combine_kernel, dim3(HWsz / 256, BZsz), dim3(256), 0, stream,
                       pvmax, pind, vmax, ind);
    hipLaunchKernelGGL(scanprep_kernel, dim3(Msz / 4, BZsz), dim3(256), 0, stream,
                       inpT, dnorm, ind, midx, kidx, uT, bkT);
    hipLaunchKernelGGL(scan_kernel, dim3(BZsz), dim3(64), 0, stream,
                       uT, bkT, vmax, midx, outT);
    hipLaunchKernelGGL(finalize_kernel, dim3(BZsz, HWsz / 64), dim3(256), 0, stream,
                       inpT, outT, ind, kidx, mp, out);
}